// Round 8
// baseline (283.540 us; speedup 1.0000x reference)
//
#include <hip/hip_runtime.h>
#include <hip/hip_bf16.h>

// ArcFace fused: cos = emb @ (w/||w||), margin at target label, softmax over batch axis.
// N=512, D=512, C=100000, S=1.  100000 = 3125 * 32 -> BC=32 divides exactly, no guards.
//
//   prep_afrag : emb f32 -> bf16 A-fragments (512 KB, L2-resident, lane-contiguous)
//   wt_kernel  : w f32 [k][c] -> bf16 B-FRAGMENTS (lane-contiguous 1KB per wave-load)
//                + per-column rsqrt(norm) in the SAME single pass (norm applied after
//                GEMM in the epilogue -- validated numerically in round 2).
//   arcface_main: barrier-free, LDS-free K-loop: per step 6 coalesced dwordx4 loads
//                (4 A + 2 B) + 8 MFMA. Fully unrolled; compiler keeps loads in flight.
//                acc[4][2]=32 AGPR, launch_bounds(512,4) -> 4 waves/SIMD.
//                tgt one-hot scan fused (1 float4/thread every other step -> labL LDS).
//                Epilogue: rnorm scale, margin, in-block column softmax.

static constexpr int DIM    = 512;
static constexpr int NROWS  = 512;
static constexpr int NCLS   = 100000;
static constexpr int BC     = 32;              // columns per block
static constexpr int BK     = 32;              // K per step
static constexpr int NSTEP  = DIM / BK;        // 16
static constexpr int MT     = NROWS / 16;      // 32
static constexpr int NBLK   = NCLS / BC;       // 3125 exact

static constexpr float COS_M = 0.87758256189037271611f;  // cos(0.5)
static constexpr float SIN_M = 0.47942553860420300027f;  // sin(0.5)
static constexpr float SCALE = 64.0f;

typedef __attribute__((ext_vector_type(8))) short bf16x8;
typedef __attribute__((ext_vector_type(4))) float f32x4;

#define MFMA16(A, B, C) __builtin_amdgcn_mfma_f32_16x16x32_bf16((A), (B), (C), 0, 0, 0)

__device__ __forceinline__ unsigned short f2bf(float f) {
  union { float f; unsigned u; } v; v.f = f;
  unsigned u = v.u;
  return (unsigned short)((u + 0x7FFFu + ((u >> 16) & 1u)) >> 16);
}

// ---------------------------------------------------------------------------
// emb [512][512] f32 -> bf16 A-fragments:
// afrag[((ks*MT+mt)*64 + lane)*8 + j] = bf16(emb[mt*16 + (lane&15)][ks*32 + (lane>>4)*8 + j])
// ---------------------------------------------------------------------------
__global__ void prep_afrag(const float* __restrict__ emb,
                           unsigned short* __restrict__ afrag) {
  const int idx = blockIdx.x * blockDim.x + threadIdx.x;  // 0..32767
  const int l  = idx & 63;
  const int mt = (idx >> 6) & 31;
  const int ks = idx >> 11;
  const int row = mt * 16 + (l & 15);
  const int k0  = ks * 32 + (l >> 4) * 8;

  unsigned short t[8];
#pragma unroll
  for (int j = 0; j < 8; ++j) t[j] = f2bf(emb[row * DIM + k0 + j]);

  uint4 v;
  v.x = (unsigned)t[0] | ((unsigned)t[1] << 16);
  v.y = (unsigned)t[2] | ((unsigned)t[3] << 16);
  v.z = (unsigned)t[4] | ((unsigned)t[5] << 16);
  v.w = (unsigned)t[6] | ((unsigned)t[7] << 16);
  *reinterpret_cast<uint4*>(&afrag[(size_t)idx * 8]) = v;
}

// ---------------------------------------------------------------------------
// wt_kernel: one block per 32-column group cb. Single pass over w (coalesced):
//  - bfrag[(((cb*16 + ks)*2 + j)*64 + lane)*8 + e] =
//        bf16(w[ks*32 + (lane>>4)*8 + e][cb*32 + j*16 + (lane&15)])
//    (lane-contiguous 1KB fragments, matching the MFMA B layout)
//  - rnorm[c] = rsqrt(sum_k w[k][c]^2)  (f32, single pass, LDS reduce)
// ---------------------------------------------------------------------------
__global__ __launch_bounds__(256)
void wt_kernel(const float* __restrict__ w,
               unsigned short* __restrict__ bfrag,
               float* __restrict__ rnorm) {
  __shared__ float S[32][33];        // k x col tile, padded
  __shared__ float NRM[32][32];      // [k-group][col] norm partials

  const int t  = threadIdx.x;
  const int cb = blockIdx.x;
  const int c0 = cb * 32;

  const int rk = t >> 3;            // 0..31 : k within pass
  const int rc = (t & 7) * 4;       // 0,4,..28 : col group (float4)

  float4 nrm4 = {0.f, 0.f, 0.f, 0.f};

  for (int p = 0; p < NSTEP; ++p) {
    // coalesced read: 32 k-rows x 32 cols
    const float4 v = *reinterpret_cast<const float4*>(
        w + (size_t)(p * BK + rk) * NCLS + c0 + rc);
    nrm4.x += v.x * v.x; nrm4.y += v.y * v.y;
    nrm4.z += v.z * v.z; nrm4.w += v.w * v.w;
    __syncthreads();                 // S free (prev pass readers done)
    *reinterpret_cast<float4*>(&S[rk][rc]) = v;
    __syncthreads();

    // fragment write: threads 0..127 -> 2 fragments (j = t>>6), 16B each
    if (t < 128) {
      const int l2 = t & 63;
      const int j  = t >> 6;
      const int col = j * 16 + (l2 & 15);
      const int kb  = (l2 >> 4) * 8;
      uint4 pk;
      pk.x = (unsigned)f2bf(S[kb + 0][col]) | ((unsigned)f2bf(S[kb + 1][col]) << 16);
      pk.y = (unsigned)f2bf(S[kb + 2][col]) | ((unsigned)f2bf(S[kb + 3][col]) << 16);
      pk.z = (unsigned)f2bf(S[kb + 4][col]) | ((unsigned)f2bf(S[kb + 5][col]) << 16);
      pk.w = (unsigned)f2bf(S[kb + 6][col]) | ((unsigned)f2bf(S[kb + 7][col]) << 16);
      *reinterpret_cast<uint4*>(
          &bfrag[(((size_t)(cb * NSTEP + p) * 2 + j) * 64 + l2) * 8]) = pk;
    }
  }

  // norm reduce: 32 partial-groups (rk) x 32 cols
  NRM[rk][rc + 0] = nrm4.x;
  NRM[rk][rc + 1] = nrm4.y;
  NRM[rk][rc + 2] = nrm4.z;
  NRM[rk][rc + 3] = nrm4.w;
  __syncthreads();
  if (t < 32) {
    float s = 0.f;
#pragma unroll
    for (int g = 0; g < 32; ++g) s += NRM[g][t];
    rnorm[c0 + t] = rsqrtf(fmaxf(s, 1e-20f));
  }
}

// ---------------------------------------------------------------------------
// Main kernel. 512 threads = 8 waves, 2 blocks/CU (launch_bounds(512,4)).
// Wave wv owns rows [wv*64, wv*64+64) x the block's 32 columns.
// K-loop: NO LDS, NO barriers, all loads lane-contiguous dwordx4.
// ---------------------------------------------------------------------------
__global__ __launch_bounds__(512, 4)
void arcface_main(const unsigned short* __restrict__ bfrag,
                  const unsigned short* __restrict__ afrag,
                  const float* __restrict__ rnorm,
                  const float* __restrict__ tgt,
                  float* __restrict__ out) {
  __shared__ float red[8][BC];
  __shared__ float colv[BC];
  __shared__ unsigned char labL[NROWS];

  const int tid = threadIdx.x;
  const int wv  = tid >> 6;
  const int l   = tid & 63;
  const int lh  = l >> 4;
  const int ll  = l & 15;
  const int c0  = blockIdx.x * BC;

  if (tid < 128) reinterpret_cast<unsigned*>(labL)[tid] = 0u;
  __syncthreads();

  // tgt scan role: thread covers rows wv*64 + (l>>3)*8 + it (it=0..7), cols (l&7)*4..+3
  const int trow0 = wv * 64 + (l >> 3) * 8;
  const int tcc   = (l & 7) * 4;
  const float* tgtp = tgt + (size_t)trow0 * NCLS + c0 + tcc;

  const unsigned short* pA = afrag + ((size_t)(wv * 4) * 64 + l) * 8;
  const unsigned short* pB = bfrag + ((size_t)(blockIdx.x * NSTEP) * 2 * 64 + l) * 8;

  f32x4 acc[4][2] = {};

#pragma unroll
  for (int ks = 0; ks < NSTEP; ++ks) {
    const bf16x8 b0 = *reinterpret_cast<const bf16x8*>(pB + (size_t)ks * 1024);
    const bf16x8 b1 = *reinterpret_cast<const bf16x8*>(pB + (size_t)ks * 1024 + 512);
    bf16x8 a[4];
#pragma unroll
    for (int i = 0; i < 4; ++i)
      a[i] = *reinterpret_cast<const bf16x8*>(pA + (size_t)(ks * MT + i) * 512);

    if ((ks & 1) == 0) {
      const int it = ks >> 1;
      const float4 tv = *reinterpret_cast<const float4*>(tgtp + (size_t)it * NCLS);
      const int trow = trow0 + it;
      if (tv.x > 0.5f) labL[trow] = (unsigned char)(tcc + 1);
      if (tv.y > 0.5f) labL[trow] = (unsigned char)(tcc + 2);
      if (tv.z > 0.5f) labL[trow] = (unsigned char)(tcc + 3);
      if (tv.w > 0.5f) labL[trow] = (unsigned char)(tcc + 4);
    }

#pragma unroll
    for (int i = 0; i < 4; ++i) {
      acc[i][0] = MFMA16(a[i], b0, acc[i][0]);
      acc[i][1] = MFMA16(a[i], b1, acc[i][1]);
    }
  }

  // ---- epilogue
  float rn[2];
#pragma unroll
  for (int j = 0; j < 2; ++j) rn[j] = rnorm[c0 + j * 16 + ll];

  __syncthreads();   // labL visibility

  int lab[4][4];
#pragma unroll
  for (int i = 0; i < 4; ++i)
#pragma unroll
    for (int q = 0; q < 4; ++q)
      lab[i][q] = (int)labL[wv * 64 + i * 16 + lh * 4 + q] - 1;  // local col or -1

  // logits: cos*rn -> clip -> margin at target -> *64; track per-column max
  float mx[2] = {-3.4e38f, -3.4e38f};
#pragma unroll
  for (int j = 0; j < 2; ++j) {
    const int jl = j * 16 + ll;
#pragma unroll
    for (int i = 0; i < 4; ++i) {
#pragma unroll
      for (int q = 0; q < 4; ++q) {
        float cosv = acc[i][j][q] * rn[j];
        cosv = fminf(fmaxf(cosv, -1.f), 1.f);
        float lg;
        if (lab[i][q] == jl) {
          const float s = sqrtf(fmaxf(1.f - cosv * cosv, 0.f));
          lg = cosv * COS_M - s * SIN_M;
        } else {
          lg = cosv;
        }
        lg *= SCALE;
        acc[i][j][q] = lg;
        mx[j] = fmaxf(mx[j], lg);
      }
    }
  }

  // softmax over the 512 rows of each column (axis=0)
#pragma unroll
  for (int j = 0; j < 2; ++j) {
    mx[j] = fmaxf(mx[j], __shfl_xor(mx[j], 16, 64));
    mx[j] = fmaxf(mx[j], __shfl_xor(mx[j], 32, 64));
  }
  if (l < 16) {
#pragma unroll
    for (int j = 0; j < 2; ++j) red[wv][j * 16 + l] = mx[j];
  }
  __syncthreads();
  if (tid < BC) {
    float m = red[0][tid];
#pragma unroll
    for (int v2 = 1; v2 < 8; ++v2) m = fmaxf(m, red[v2][tid]);
    colv[tid] = m;
  }
  __syncthreads();
  float cmax[2];
#pragma unroll
  for (int j = 0; j < 2; ++j) cmax[j] = colv[j * 16 + ll];

  float sme[2] = {0.f, 0.f};
#pragma unroll
  for (int j = 0; j < 2; ++j)
#pragma unroll
    for (int i = 0; i < 4; ++i)
#pragma unroll
      for (int q = 0; q < 4; ++q) {
        const float e = __expf(acc[i][j][q] - cmax[j]);
        acc[i][j][q] = e;
        sme[j] += e;
      }
#pragma unroll
  for (int j = 0; j < 2; ++j) {
    sme[j] += __shfl_xor(sme[j], 16, 64);
    sme[j] += __shfl_xor(sme[j], 32, 64);
  }
  __syncthreads();
  if (l < 16) {
#pragma unroll
    for (int j = 0; j < 2; ++j) red[wv][j * 16 + l] = sme[j];
  }
  __syncthreads();
  if (tid < BC) {
    float s = 0.f;
#pragma unroll
    for (int v2 = 0; v2 < 8; ++v2) s += red[v2][tid];
    colv[tid] = s;
  }
  __syncthreads();

  float rs[2];
#pragma unroll
  for (int j = 0; j < 2; ++j) rs[j] = 1.0f / colv[j * 16 + ll];

#pragma unroll
  for (int j = 0; j < 2; ++j) {
    const int cj = c0 + j * 16 + ll;
#pragma unroll
    for (int i = 0; i < 4; ++i) {
#pragma unroll
      for (int q = 0; q < 4; ++q) {
        const int row = wv * 64 + i * 16 + lh * 4 + q;
        out[(size_t)row * NCLS + cj] = acc[i][j][q] * rs[j];
      }
    }
  }
}

extern "C" void kernel_launch(void* const* d_in, const int* in_sizes, int n_in,
                              void* d_out, int out_size, void* d_ws, size_t ws_size,
                              hipStream_t stream) {
  const float* emb = (const float*)d_in[0];   // [512][512]
  const float* w   = (const float*)d_in[1];   // [512][100000]
  const float* tgt = (const float*)d_in[2];   // [512][100000]
  float* out = (float*)d_out;                 // [512][100000]

  char* ws = (char*)d_ws;
  unsigned short* afrag = (unsigned short*)(ws + 4096);          // 512 KB
  float* rnorm          = (float*)(ws + (1u << 20));             // 400 KB
  unsigned short* bfrag = (unsigned short*)(ws + (2u << 20));    // 100 MB

  prep_afrag<<<64, 512, 0, stream>>>(emb, afrag);
  wt_kernel<<<NBLK, 256, 0, stream>>>(w, bfrag, rnorm);
  arcface_main<<<NBLK, 512, 0, stream>>>(bfrag, afrag, rnorm, tgt, out);
}